// Round 12
// baseline (265.040 us; speedup 1.0000x reference)
//
#include <hip/hip_runtime.h>

// ChannelBlockImportanceGate: B=8, C=256, H=W=132, BLOCK=8, KEEP_RATIO=0.25
// Output = hard top-72 block mask (of 289 blocks) upsampled 8x, per (b,c) plane.
// Straight-through soft blend cancels numerically -> output is the hard mask.
//
// v12: decisive read-path probe as a real candidate. Eleven variants show
// reads of feats capped at <=2 TB/s in EVERY structure that feeds LDS, while
// write-dominated kernels hit 5.2-6.6 TB/s. K1 below is the exact m13
// 6.29-TB/s copy shape (flat grid-stride, load -> 3 VALU -> plain store, no
// LDS/barriers/atomics): reads 142.6 MB, writes 17.4 MB of per-float4 |sums|
// to workspace. K2 = verified v10 machinery (LDS bins -> f32-bit keys ->
// wave-0 radix select -> NT float4 upsample stores) reading the 8x-smaller
// sum array. Monolith v10 fallback if workspace < 35.7 MB.

#define HH 132
#define WW 132
#define NB 17            // blocks per side
#define TOTAL 289        // NB*NB
#define NPAD 320         // padded keys (5 regs x 64 lanes)
#define KEEP 72          // round(289*0.25)
#define NTH 256
#define NC4 33           // float4s per row (132/4)
#define NV 4356          // float4s per plane
#define PLANES 2048
#define NTOT (PLANES * NV)   // 8,921,088 float4s total

typedef float floatx4 __attribute__((ext_vector_type(4)));

// ---------------- K1: m13-shape sum stream (the probe) ----------------
__global__ __launch_bounds__(NTH)
void sum_kernel(const float4* __restrict__ in4,
                float* __restrict__ ws_sum) {
    const int stride = gridDim.x * NTH;
    for (int i = blockIdx.x * NTH + threadIdx.x; i < NTOT; i += stride) {
        const float4 x = in4[i];
        ws_sum[i] = (fabsf(x.x) + fabsf(x.y)) + (fabsf(x.z) + fabsf(x.w));
    }
}

// ---------------- K2: bins -> radix select -> upsample write ----------------
__global__ __launch_bounds__(NTH)
void mask_kernel(const float* __restrict__ ws_sum,
                 const int* __restrict__ enabled_p,
                 float4* __restrict__ out4) {
    const int plane = blockIdx.x;
    const int t = threadIdx.x;
    const float* __restrict__ sp = ws_sum + (size_t)plane * NV;

    __shared__ __align__(16) float    s_e[NV];       // 17424 B
    __shared__ __align__(16) unsigned s_key[NPAD];
    __shared__ float s_hard[TOTAL];
    __shared__ unsigned s_T;
    __shared__ int s_kT;

    // load per-float4 sums (coalesced f32 stream, 17.4 KB/plane)
    #pragma unroll
    for (int k = 0; k < 18; ++k) {
        const int v = t + k * NTH;
        if (v < NV) s_e[v] = sp[v];
    }
    __syncthreads();

    // block scores (16 bins; right edge 8; bottom 8/4); key = f32 bits
    for (int b = t; b < NPAD; b += NTH) {
        unsigned key = 0u;
        if (b < TOTAL) {
            const int br = b / NB;
            const int bc = b - br * NB;
            const int nr = (br == NB - 1) ? 4 : 8;
            const int base = (br * 8) * NC4 + 2 * bc;
            double sum = 0.0;
            if (bc < NB - 1) {
                for (int rr = 0; rr < nr; ++rr)
                    sum += (double)s_e[base + rr * NC4]
                         + (double)s_e[base + rr * NC4 + 1];
            } else {
                for (int rr = 0; rr < nr; ++rr)
                    sum += (double)s_e[base + rr * NC4];
            }
            key = __float_as_uint((float)sum);
        }
        s_key[b] = key;                              // pads (289..319) = 0
    }
    __syncthreads();

    // wave-0 radix select: T = 72nd-largest key, kT = tie slots (v10)
    if (t < 64) {
        unsigned K0 = s_key[t];
        unsigned K1 = s_key[64 + t];
        unsigned K2 = s_key[128 + t];
        unsigned K3 = s_key[192 + t];
        unsigned K4 = s_key[256 + t];
        unsigned P = 0u;
        int k = KEEP;
        #pragma unroll
        for (int b = 31; b >= 0; --b) {
            const unsigned hi = (P >> b) | 1u;
            int cnt = __popcll(__ballot((K0 >> b) == hi))
                    + __popcll(__ballot((K1 >> b) == hi))
                    + __popcll(__ballot((K2 >> b) == hi))
                    + __popcll(__ballot((K3 >> b) == hi))
                    + __popcll(__ballot((K4 >> b) == hi));
            if (cnt >= k) P |= (1u << b);
            else          k -= cnt;
        }
        if (t == 0) { s_T = P; s_kT = k; }
    }
    __syncthreads();

    // mask: key>T keeps; key==T keeps first kT in index order (stable)
    const int en = *enabled_p;
    const unsigned T = s_T;
    const int kT = s_kT;
    for (int i = t; i < TOTAL; i += NTH) {
        const unsigned ki = s_key[i];
        float m;
        if (!en || ki > T) {
            m = 1.0f;
        } else if (ki < T) {
            m = 0.0f;
        } else {
            int eq = 0;
            for (int j = 0; j < i; ++j) eq += (int)(s_key[j] == T);
            m = (eq < kT) ? 1.0f : 0.0f;
        }
        s_hard[i] = m;
    }
    __syncthreads();

    // upsample 8x, NT float4 stores (verified fast: 5.2 TB/s in v4)
    floatx4* __restrict__ op = (floatx4*)(out4 + (size_t)plane * NV);
    for (int v = t; v < NV; v += NTH) {
        const int base = v * 4;
        const int row = base / WW;
        const int col = base - row * WW;
        const float m = s_hard[(row >> 3) * NB + (col >> 3)];
        const floatx4 mv = {m, m, m, m};
        __builtin_nontemporal_store(mv, &op[v]);
    }
}

// ---------------- Fallback: v10 monolith (ws too small) ----------------
__global__ __launch_bounds__(NTH)
void gate_mono(const float4* __restrict__ feats4,
               const int* __restrict__ enabled_p,
               float4* __restrict__ out4) {
    const int plane = blockIdx.x;
    const int t = threadIdx.x;
    const float4* __restrict__ fp = feats4 + (size_t)plane * NV;

    __shared__ __align__(16) float    s_e[NV];
    __shared__ __align__(16) unsigned s_key[NPAD];
    __shared__ float s_hard[TOTAL];
    __shared__ unsigned s_T;
    __shared__ int s_kT;

    #pragma unroll
    for (int k = 0; k < 18; ++k) {
        const int v = t + k * NTH;
        if (v < NV) {
            const float4 x = fp[v];
            s_e[v] = (fabsf(x.x) + fabsf(x.y)) + (fabsf(x.z) + fabsf(x.w));
        }
    }
    __syncthreads();
    for (int b = t; b < NPAD; b += NTH) {
        unsigned key = 0u;
        if (b < TOTAL) {
            const int br = b / NB;
            const int bc = b - br * NB;
            const int nr = (br == NB - 1) ? 4 : 8;
            const int base = (br * 8) * NC4 + 2 * bc;
            double sum = 0.0;
            if (bc < NB - 1) {
                for (int rr = 0; rr < nr; ++rr)
                    sum += (double)s_e[base + rr * NC4]
                         + (double)s_e[base + rr * NC4 + 1];
            } else {
                for (int rr = 0; rr < nr; ++rr)
                    sum += (double)s_e[base + rr * NC4];
            }
            key = __float_as_uint((float)sum);
        }
        s_key[b] = key;
    }
    __syncthreads();
    if (t < 64) {
        unsigned K0 = s_key[t];
        unsigned K1 = s_key[64 + t];
        unsigned K2 = s_key[128 + t];
        unsigned K3 = s_key[192 + t];
        unsigned K4 = s_key[256 + t];
        unsigned P = 0u;
        int k = KEEP;
        #pragma unroll
        for (int b = 31; b >= 0; --b) {
            const unsigned hi = (P >> b) | 1u;
            int cnt = __popcll(__ballot((K0 >> b) == hi))
                    + __popcll(__ballot((K1 >> b) == hi))
                    + __popcll(__ballot((K2 >> b) == hi))
                    + __popcll(__ballot((K3 >> b) == hi))
                    + __popcll(__ballot((K4 >> b) == hi));
            if (cnt >= k) P |= (1u << b);
            else          k -= cnt;
        }
        if (t == 0) { s_T = P; s_kT = k; }
    }
    __syncthreads();
    const int en = *enabled_p;
    const unsigned T = s_T;
    const int kT = s_kT;
    for (int i = t; i < TOTAL; i += NTH) {
        const unsigned ki = s_key[i];
        float m;
        if (!en || ki > T)      m = 1.0f;
        else if (ki < T)        m = 0.0f;
        else {
            int eq = 0;
            for (int j = 0; j < i; ++j) eq += (int)(s_key[j] == T);
            m = (eq < kT) ? 1.0f : 0.0f;
        }
        s_hard[i] = m;
    }
    __syncthreads();
    floatx4* __restrict__ op = (floatx4*)(out4 + (size_t)plane * NV);
    for (int v = t; v < NV; v += NTH) {
        const int base = v * 4;
        const int row = base / WW;
        const int col = base - row * WW;
        const float m = s_hard[(row >> 3) * NB + (col >> 3)];
        const floatx4 mv = {m, m, m, m};
        __builtin_nontemporal_store(mv, &op[v]);
    }
}

extern "C" void kernel_launch(void* const* d_in, const int* in_sizes, int n_in,
                              void* d_out, int out_size, void* d_ws, size_t ws_size,
                              hipStream_t stream) {
    const float4* feats = (const float4*)d_in[0];
    const int* enabled = (const int*)d_in[1];
    float4* out = (float4*)d_out;
    const size_t need = (size_t)NTOT * sizeof(float);    // 35.7 MB
    if (d_ws != nullptr && ws_size >= need) {
        float* wsum = (float*)d_ws;
        sum_kernel<<<4096, NTH, 0, stream>>>(feats, wsum);
        mask_kernel<<<PLANES, NTH, 0, stream>>>(wsum, enabled, out);
    } else {
        gate_mono<<<PLANES, NTH, 0, stream>>>(feats, enabled, out);
    }
}

// Round 13
// 245.876 us; speedup vs baseline: 1.0779x; 1.0779x over previous
//
#include <hip/hip_runtime.h>

// ChannelBlockImportanceGate: B=8, C=256, H=W=132, BLOCK=8, KEEP_RATIO=0.25
// Output = hard top-72 block mask (of 289 blocks) upsampled 8x, per (b,c) plane.
// Straight-through soft blend cancels numerically -> output is the hard mask.
//
// v13 = v10 monolith + NONTEMPORAL LOADS on the input stream (single-variable
// probe). Evidence: 13 variants split cleanly into read-heavy kernels (all
// ~2.0-2.3 TB/s: monolith/split/atomic-free/DMA/flat-stream) vs write-
// dominated kernels (5.2-6.6 TB/s). FETCH_SIZE is pinned at input/2 every
// round: input+output (285 MB) thrash the 256 MB L3, so half the reads are
// L3 hits. Hypothesis: L3-hit reads are the ~2 TB/s slow path; NT loads
// (nt/sc bits -> no L2/L3 allocation) force HBM streaming for the reads.
// Everything else byte-identical to v10 (radix select, NT stores).

#define HH 132
#define WW 132
#define NB 17            // blocks per side
#define TOTAL 289        // NB*NB
#define NPAD 320         // padded keys (5 regs x 64 lanes)
#define KEEP 72          // round(289*0.25)
#define NTH 256
#define NC4 33           // float4s per row (132/4)
#define NV 4356          // float4s per plane
#define PLANES 2048

typedef float floatx4 __attribute__((ext_vector_type(4)));

__global__ __launch_bounds__(NTH)
void gate_kernel(const float4* __restrict__ feats4,
                 const int* __restrict__ enabled_p,
                 float4* __restrict__ out4) {
    const int plane = blockIdx.x;
    const int t = threadIdx.x;
    const floatx4* __restrict__ fp =
        (const floatx4*)(feats4 + (size_t)plane * NV);

    __shared__ __align__(16) float    s_e[NV];       // 17424 B
    __shared__ __align__(16) unsigned s_key[NPAD];   // 1280 B
    __shared__ float s_hard[TOTAL];                  // 1156 B
    __shared__ unsigned s_T;
    __shared__ int s_kT;

    // ---- Phase A: coalesced NT stream, per-float4 f32 |sum| -> LDS bin ----
    #pragma unroll
    for (int k = 0; k < 18; ++k) {
        const int v = t + k * NTH;                   // 18*256 covers 4356
        if (v < NV) {
            const floatx4 x = __builtin_nontemporal_load(&fp[v]);
            s_e[v] = (fabsf(x.x) + fabsf(x.y)) + (fabsf(x.z) + fabsf(x.w));
        }
    }
    __syncthreads();

    // ---- Phase B: block scores (16 bins; right edge 8; bottom 8/4) ----
    // Key = f32 bits of the non-negative score: order-monotone as u32.
    for (int b = t; b < NPAD; b += NTH) {
        unsigned key = 0u;
        if (b < TOTAL) {
            const int br = b / NB;                   // magic-mul
            const int bc = b - br * NB;
            const int nr = (br == NB - 1) ? 4 : 8;   // bottom stripe: 4 rows
            const int base = (br * 8) * NC4 + 2 * bc;
            double sum = 0.0;
            if (bc < NB - 1) {
                for (int rr = 0; rr < nr; ++rr)
                    sum += (double)s_e[base + rr * NC4]
                         + (double)s_e[base + rr * NC4 + 1];
            } else {
                for (int rr = 0; rr < nr; ++rr)
                    sum += (double)s_e[base + rr * NC4];
            }
            key = __float_as_uint((float)sum);
        }
        s_key[b] = key;                              // pads (289..319) = 0
    }
    __syncthreads();

    // ---- Phase C: radix select in wave 0 (verified v10) ----
    if (t < 64) {
        unsigned K0 = s_key[t];
        unsigned K1 = s_key[64 + t];
        unsigned K2 = s_key[128 + t];
        unsigned K3 = s_key[192 + t];
        unsigned K4 = s_key[256 + t];
        unsigned P = 0u;
        int k = KEEP;
        #pragma unroll
        for (int b = 31; b >= 0; --b) {
            const unsigned hi = (P >> b) | 1u;
            int cnt = __popcll(__ballot((K0 >> b) == hi))
                    + __popcll(__ballot((K1 >> b) == hi))
                    + __popcll(__ballot((K2 >> b) == hi))
                    + __popcll(__ballot((K3 >> b) == hi))
                    + __popcll(__ballot((K4 >> b) == hi));
            if (cnt >= k) P |= (1u << b);
            else          k -= cnt;
        }
        if (t == 0) { s_T = P; s_kT = k; }
    }
    __syncthreads();

    // ---- Mask: key>T keeps; key==T keeps first kT in index order ----
    const int en = *enabled_p;
    const unsigned T = s_T;
    const int kT = s_kT;
    for (int i = t; i < TOTAL; i += NTH) {
        const unsigned ki = s_key[i];
        float m;
        if (!en || ki > T) {
            m = 1.0f;
        } else if (ki < T) {
            m = 0.0f;
        } else {                                     // tie (rare): stable order
            int eq = 0;
            for (int j = 0; j < i; ++j) eq += (int)(s_key[j] == T);
            m = (eq < kT) ? 1.0f : 0.0f;
        }
        s_hard[i] = m;
    }
    __syncthreads();

    // ---- Phase D: upsample 8x, nontemporal float4 stores (verified) ----
    floatx4* __restrict__ op = (floatx4*)(out4 + (size_t)plane * NV);
    for (int v = t; v < NV; v += NTH) {
        const int base = v * 4;
        const int row = base / WW;                   // magic-mul
        const int col = base - row * WW;
        const float m = s_hard[(row >> 3) * NB + (col >> 3)];
        const floatx4 mv = {m, m, m, m};
        __builtin_nontemporal_store(mv, &op[v]);
    }
}

extern "C" void kernel_launch(void* const* d_in, const int* in_sizes, int n_in,
                              void* d_out, int out_size, void* d_ws, size_t ws_size,
                              hipStream_t stream) {
    const float4* feats = (const float4*)d_in[0];
    const int* enabled = (const int*)d_in[1];
    float4* out = (float4*)d_out;
    gate_kernel<<<PLANES, NTH, 0, stream>>>(feats, enabled, out);
}